// Round 10
// baseline (528.673 us; speedup 1.0000x reference)
//
#include <hip/hip_runtime.h>
#include <hip/hip_bf16.h>

// Relative-position causal attention, B=4 H=16 Q=K=1024 D=64 (fp32 in/out).
// d_out = [output (BH*Q*D) | p_attn (BH*Q*K)] fp32.
// K1 k_scores: content scores, barrier-free per-wave glld pipeline (counted vmcnt).
// K2 k_rel_pr: per-q block; pass1 rel+exp (barrier-free wave pipeline) + row sum;
//              pass2 normalize P in place + out = Pn@bigr_v[q] (direct strided B).
// K3 k_pv: out += Pn @ V.

#define BH 64
#define SQ 1024
#define SK 1024
#define DH 64
#define SCALE 0.125f

typedef __attribute__((ext_vector_type(4))) float f32x4;
typedef __attribute__((ext_vector_type(8))) unsigned short ushort8;
typedef __attribute__((ext_vector_type(8))) __bf16 bf16x8;

static __device__ inline unsigned short f2bf(float x) {
    unsigned u = __float_as_uint(x);
    unsigned r = u + 0x7FFFu + ((u >> 16) & 1u);
    return (unsigned short)(r >> 16);
}
static __device__ inline float bf2f(unsigned short s) {
    return __uint_as_float(((unsigned)s) << 16);
}

struct Frag2 { bf16x8 h, l; };

static __device__ inline Frag2 load_split(const float* __restrict__ p) {
    float4 x0 = *reinterpret_cast<const float4*>(p);
    float4 x1 = *reinterpret_cast<const float4*>(p + 4);
    float v[8] = {x0.x, x0.y, x0.z, x0.w, x1.x, x1.y, x1.z, x1.w};
    ushort8 uh, ul;
#pragma unroll
    for (int j = 0; j < 8; ++j) {
        unsigned short h = f2bf(v[j]);
        float r = v[j] - bf2f(h);
        uh[j] = h;
        ul[j] = f2bf(r);
    }
    Frag2 f;
    f.h = __builtin_bit_cast(bf16x8, uh);
    f.l = __builtin_bit_cast(bf16x8, ul);
    return f;
}

static __device__ inline bf16x8 pack_bf8(float4 x0, float4 x1) {
    float v[8] = {x0.x, x0.y, x0.z, x0.w, x1.x, x1.y, x1.z, x1.w};
    ushort8 u;
#pragma unroll
    for (int j = 0; j < 8; ++j) u[j] = f2bf(v[j]);
    return __builtin_bit_cast(bf16x8, u);
}

static __device__ inline bf16x8 load_bf8(const float* __restrict__ p) {
    float4 x0 = *reinterpret_cast<const float4*>(p);
    float4 x1 = *reinterpret_cast<const float4*>(p + 4);
    return pack_bf8(x0, x1);
}

static __device__ inline bf16x8 load_bf8_strided(const float* __restrict__ p, int stride) {
    ushort8 u;
#pragma unroll
    for (int j = 0; j < 8; ++j) u[j] = f2bf(p[(size_t)j * stride]);
    return __builtin_bit_cast(bf16x8, u);
}

#define MFMA(a, b, c) __builtin_amdgcn_mfma_f32_16x16x32_bf16((a), (b), (c), 0, 0, 0)

// async global -> LDS, 16B per lane; lds dest is wave-uniform base + lane*16
#define GLLD(g, s)                                                              \
    __builtin_amdgcn_global_load_lds(                                           \
        (const __attribute__((address_space(1))) void*)(g),                     \
        (__attribute__((address_space(3))) void*)(s), 16, 0, 0)

// stage a 64x64 fp32 tile (rows at src0 + row*DH) into buf[b]; WAVE-PRIVATE:
// wave w stages rows [w*16, w*16+16) and later reads only those rows.
// source pre-swizzled (chunk ^= row&7) so linear LDS + swizzled reads match.
#define STAGE64(src0, b)                                                        \
    do {                                                                        \
        _Pragma("unroll")                                                       \
        for (int j_ = 0; j_ < 4; ++j_) {                                        \
            const int idx_ = w * 256 + j_ * 64 + l;                             \
            const int row_ = idx_ >> 4;                                         \
            const int g_ = (idx_ & 15) ^ (row_ & 7);                            \
            GLLD((src0) + (size_t)row_ * DH + g_ * 4,                           \
                 &buf[b][w * 256 + j_ * 64]);                                   \
        }                                                                       \
    } while (0)

#define WAITV4()                                                                \
    do {                                                                        \
        asm volatile("s_waitcnt vmcnt(4)" ::: "memory");                        \
        __builtin_amdgcn_sched_barrier(0);                                      \
    } while (0)
#define WAITV0()                                                                \
    do {                                                                        \
        asm volatile("s_waitcnt vmcnt(0)" ::: "memory");                        \
        __builtin_amdgcn_sched_barrier(0);                                      \
    } while (0)

// ---------------- K1: content scores Q@K^T * scale -> P (zeros above diag).
// Block = (q-tile 64, bh). Barrier-free: LDS is wave-private, counted vmcnt.
__global__ __launch_bounds__(256, 4) void k_scores(const float* __restrict__ qp,
                                                   const float* __restrict__ kp,
                                                   float* __restrict__ P) {
    __shared__ float4 buf[2][1024];
    const int qt = 15 - (int)blockIdx.x;  // big first
    const int bh = blockIdx.y;
    const int tid = threadIdx.x;
    const int w = tid >> 6, l = tid & 63;
    const int lm = l & 15, lg = l >> 4;
    const int q0 = qt * 64;

    Frag2 qh0[4], qh1[4];
#pragma unroll
    for (int nt = 0; nt < 4; ++nt) {
        const float* qrow = qp + ((size_t)bh * SQ + q0 + nt * 16 + lm) * DH + lg * 8;
        qh0[nt] = load_split(qrow);
        qh1[nt] = load_split(qrow + 32);
    }
    const float* kb = kp + (size_t)bh * SK * DH;
    const int nt_ = qt + 1;

    STAGE64(kb, 0);
#pragma unroll 1
    for (int t = 0; t < nt_; ++t) {
        if (t + 1 < nt_) STAGE64(kb + (size_t)(t + 1) * 64 * DH, (t + 1) & 1);
        WAITV4();  // stage(t) landed; stage(t+1) still in flight
        const float4* L = buf[t & 1];
        const int R = w * 16 + lm;
        const int sw = R & 7;
        float4 f0 = L[R * 16 + ((2 * lg) ^ sw)];
        float4 f1 = L[R * 16 + ((2 * lg + 1) ^ sw)];
        float4 f2 = L[R * 16 + ((8 + 2 * lg) ^ sw)];
        float4 f3 = L[R * 16 + ((9 + 2 * lg) ^ sw)];
        bf16x8 alo = pack_bf8(f0, f1);
        bf16x8 ahi = pack_bf8(f2, f3);
        const int kq = t * 64 + w * 16 + lg * 4;
        const bool diag = (t == qt);
#pragma unroll
        for (int nt = 0; nt < 4; ++nt) {
            f32x4 acc = {0.f, 0.f, 0.f, 0.f};
            acc = MFMA(alo, qh0[nt].h, acc);
            acc = MFMA(alo, qh0[nt].l, acc);
            acc = MFMA(ahi, qh1[nt].h, acc);
            acc = MFMA(ahi, qh1[nt].l, acc);
            const int qe = q0 + nt * 16 + lm;
            float ov[4];
#pragma unroll
            for (int r = 0; r < 4; ++r) {
                float v = acc[r] * SCALE;
                ov[r] = (!diag || (kq + r <= qe)) ? v : 0.f;
            }
            float4 o;
            o.x = ov[0]; o.y = ov[1]; o.z = ov[2]; o.w = ov[3];
            *reinterpret_cast<float4*>(&P[((size_t)bh * SQ + qe) * SK + kq]) = o;
        }
    }
    // zero-fill tiles fully above the diagonal
    const float4 z = {0.f, 0.f, 0.f, 0.f};
#pragma unroll 1
    for (int t = nt_; t < 16; ++t) {
        const int kq = t * 64 + w * 16 + lg * 4;
#pragma unroll
        for (int nt = 0; nt < 4; ++nt) {
            const int qe = q0 + nt * 16 + lm;
            *reinterpret_cast<float4*>(&P[((size_t)bh * SQ + qe) * SK + kq]) = z;
        }
    }
}

// ---------------- K2: fused rel+exp+normalize+P@bigr_v. Block per q.
__global__ __launch_bounds__(256, 4) void k_rel_pr(const float* __restrict__ query,
                                                   const float* __restrict__ bigr_k,
                                                   const float* __restrict__ bigr_v,
                                                   float* __restrict__ P,
                                                   float* __restrict__ out) {
    __shared__ float4 buf[2][1024];
    __shared__ float red[4][64];
    __shared__ float rsum[64];
    const int q = SQ - 1 - (int)blockIdx.x;  // big rows first
    const int KE = q + 1;
    const int nt_ = (KE + 63) >> 6;
    const int tid = threadIdx.x;
    const int w = tid >> 6, l = tid & 63;
    const int lm = l & 15, lg = l >> 4;

    // ---- pass 1: e = exp(content + rel), row sums; barrier-free pipeline ----
    Frag2 qh0[4], qh1[4];
    float* prow[4];
#pragma unroll
    for (int nt = 0; nt < 4; ++nt) {
        const int bh = nt * 16 + lm;
        const float* qrow = query + ((size_t)bh * SQ + q) * DH + lg * 8;
        qh0[nt] = load_split(qrow);
        qh1[nt] = load_split(qrow + 32);
        prow[nt] = P + ((size_t)bh * SQ + q) * SK;
    }
    const float* bk = bigr_k + (size_t)q * SK * DH;
    float lsum[4] = {0.f, 0.f, 0.f, 0.f};

    STAGE64(bk, 0);
#pragma unroll 1
    for (int t = 0; t < nt_; ++t) {
        const int kq = t * 64 + w * 16 + lg * 4;
        float4 pc[4];
#pragma unroll
        for (int nt = 0; nt < 4; ++nt)
            pc[nt] = *reinterpret_cast<const float4*>(prow[nt] + kq);
        if (t + 1 < nt_) {
            STAGE64(bk + (size_t)(t + 1) * 64 * DH, (t + 1) & 1);
            WAITV4();  // stage(t)+pc landed; stage(t+1) in flight
        } else {
            WAITV0();
        }
        const float4* L = buf[t & 1];
        const int R = w * 16 + lm;
        const int sw = R & 7;
        float4 f0 = L[R * 16 + ((2 * lg) ^ sw)];
        float4 f1 = L[R * 16 + ((2 * lg + 1) ^ sw)];
        float4 f2 = L[R * 16 + ((8 + 2 * lg) ^ sw)];
        float4 f3 = L[R * 16 + ((9 + 2 * lg) ^ sw)];
        bf16x8 alo = pack_bf8(f0, f1);
        bf16x8 ahi = pack_bf8(f2, f3);
#pragma unroll
        for (int nt = 0; nt < 4; ++nt) {
            f32x4 acc = {0.f, 0.f, 0.f, 0.f};
            acc = MFMA(alo, qh0[nt].h, acc);
            acc = MFMA(alo, qh0[nt].l, acc);
            acc = MFMA(ahi, qh1[nt].h, acc);
            acc = MFMA(ahi, qh1[nt].l, acc);
            const float4 c = pc[nt];
            float cv[4] = {c.x, c.y, c.z, c.w};
            float ov[4];
#pragma unroll
            for (int r = 0; r < 4; ++r) {
                float e = (kq + r < KE) ? __expf(cv[r] + acc[r] * SCALE) : 0.f;
                ov[r] = e;
                lsum[nt] += e;
            }
            float4 o;
            o.x = ov[0]; o.y = ov[1]; o.z = ov[2]; o.w = ov[3];
            *reinterpret_cast<float4*>(prow[nt] + kq) = o;
        }
    }

    // ---- row-sum reduce -> recip in LDS (only block-wide syncs) ----
#pragma unroll
    for (int nt = 0; nt < 4; ++nt) {
        float v = lsum[nt];
        v += __shfl_xor(v, 16);
        v += __shfl_xor(v, 32);
        if (l < 16) red[w][nt * 16 + l] = v;
    }
    __syncthreads();
    if (tid < 64)
        rsum[tid] = 1.0f / (red[0][tid] + red[1][tid] + red[2][tid] + red[3][tid]);
    __syncthreads();

    // ---- pass 2: normalize P in place + out = Pn @ bigr_v[q]; no barriers ----
    const int bh0 = w * 16;
    const float* bv = bigr_v + (size_t)q * SK * DH;
    float* arow0 = P + ((size_t)(bh0 + lm) * SQ + q) * SK + lg * 8;
    const float nrm = rsum[bh0 + lm];
    f32x4 acc[4] = {{0.f,0.f,0.f,0.f},{0.f,0.f,0.f,0.f},{0.f,0.f,0.f,0.f},{0.f,0.f,0.f,0.f}};
#pragma unroll 2
    for (int k0 = 0; k0 < KE; k0 += 32) {
        float* arow = arow0 + k0;
        float4 x0 = *reinterpret_cast<const float4*>(arow);
        float4 x1 = *reinterpret_cast<const float4*>(arow + 4);
        float4 y0 = {x0.x * nrm, x0.y * nrm, x0.z * nrm, x0.w * nrm};
        float4 y1 = {x1.x * nrm, x1.y * nrm, x1.z * nrm, x1.w * nrm};
        *reinterpret_cast<float4*>(arow) = y0;       // final normalized p_attn
        *reinterpret_cast<float4*>(arow + 4) = y1;
        bf16x8 a = pack_bf8(y0, y1);
#pragma unroll
        for (int nt = 0; nt < 4; ++nt) {
            const float* bcol = bv + (size_t)(k0 + lg * 8) * DH + nt * 16 + lm;
            bf16x8 b = load_bf8_strided(bcol, DH);
            acc[nt] = MFMA(a, b, acc[nt]);
        }
    }
#pragma unroll
    for (int nt = 0; nt < 4; ++nt)
#pragma unroll
        for (int r = 0; r < 4; ++r)
            out[((size_t)(bh0 + lg * 4 + r) * SQ + q) * DH + nt * 16 + lm] = acc[nt][r];
}

// ---------------- K3: out += Pn @ V (per bh, q-tiles of 64)
__global__ __launch_bounds__(256) void k_pv(const float* __restrict__ P,
                                            const float* __restrict__ V,
                                            float* __restrict__ out) {
    const int qt = 15 - (int)blockIdx.x;  // big tiles first
    const int bh = blockIdx.y;
    const int tid = threadIdx.x;
    const int w = tid >> 6, l = tid & 63;
    const int lm = l & 15, lg = l >> 4;
    const int q0 = qt * 64 + w * 16;

    f32x4 acc[4] = {{0.f,0.f,0.f,0.f},{0.f,0.f,0.f,0.f},{0.f,0.f,0.f,0.f},{0.f,0.f,0.f,0.f}};
    const int kend = q0 + 16;
    for (int k0 = 0; k0 < kend; k0 += 32) {
        const float* arow = P + ((size_t)bh * SQ + q0 + lm) * SK + k0 + lg * 8;
        bf16x8 a = load_bf8(arow);
#pragma unroll
        for (int nt = 0; nt < 4; ++nt) {
            const float* bcol = V + ((size_t)bh * SK + k0 + lg * 8) * DH + nt * 16 + lm;
            bf16x8 b = load_bf8_strided(bcol, DH);
            acc[nt] = MFMA(a, b, acc[nt]);
        }
    }
#pragma unroll
    for (int nt = 0; nt < 4; ++nt)
#pragma unroll
        for (int r = 0; r < 4; ++r)
            out[((size_t)bh * SQ + q0 + lg * 4 + r) * DH + nt * 16 + lm] += acc[nt][r];
}

extern "C" void kernel_launch(void* const* d_in, const int* in_sizes, int n_in,
                              void* d_out, int out_size, void* d_ws, size_t ws_size,
                              hipStream_t stream) {
    const float* query  = (const float*)d_in[0];
    const float* key    = (const float*)d_in[1];
    const float* value  = (const float*)d_in[2];
    const float* bigr_k = (const float*)d_in[3];
    const float* bigr_v = (const float*)d_in[4];
    float* out = (float*)d_out;                       // BH*SQ*DH
    float* P   = out + (size_t)BH * SQ * DH;          // BH*SQ*SK

    k_scores<<<dim3(16, BH), 256, 0, stream>>>(query, key, P);
    k_rel_pr<<<dim3(SQ), 256, 0, stream>>>(query, bigr_k, bigr_v, P, out);
    k_pv<<<dim3(16, BH), 256, 0, stream>>>(P, value, out);
}

// Round 11
// 500.911 us; speedup vs baseline: 1.0554x; 1.0554x over previous
//
#include <hip/hip_runtime.h>
#include <hip/hip_bf16.h>

// Relative-position causal attention, B=4 H=16 Q=K=1024 D=64 (fp32 in/out).
// d_out = [output (BH*Q*D) | p_attn (BH*Q*K)] fp32.
// K1 k_scores: content scores; glld double-buffer, ONE barrier/tile, stage after barrier.
// K2 k_rel_pr: per-q block (balanced remap); pass1 rel+exp, overlapped staging;
//              pass2 normalize P in place + out = Pn@bigr_v[q], dbuf vt, 1 barrier/step.
// K3 k_pv: out += Pn @ V.

#define BH 64
#define SQ 1024
#define SK 1024
#define DH 64
#define SCALE 0.125f

typedef __attribute__((ext_vector_type(4))) float f32x4;
typedef __attribute__((ext_vector_type(8))) unsigned short ushort8;
typedef __attribute__((ext_vector_type(8))) __bf16 bf16x8;

static __device__ inline unsigned short f2bf(float x) {
    unsigned u = __float_as_uint(x);
    unsigned r = u + 0x7FFFu + ((u >> 16) & 1u);
    return (unsigned short)(r >> 16);
}
static __device__ inline float bf2f(unsigned short s) {
    return __uint_as_float(((unsigned)s) << 16);
}

struct Frag2 { bf16x8 h, l; };

// Load 8 fp32, scale, split into hi/lo bf16 fragments (hi+lo == scaled value).
static __device__ inline Frag2 load_split(const float* __restrict__ p, float scale) {
    float4 x0 = *reinterpret_cast<const float4*>(p);
    float4 x1 = *reinterpret_cast<const float4*>(p + 4);
    float v[8] = {x0.x, x0.y, x0.z, x0.w, x1.x, x1.y, x1.z, x1.w};
    ushort8 uh, ul;
#pragma unroll
    for (int j = 0; j < 8; ++j) {
        float s = v[j] * scale;
        unsigned short h = f2bf(s);
        float r = s - bf2f(h);
        uh[j] = h;
        ul[j] = f2bf(r);
    }
    Frag2 f;
    f.h = __builtin_bit_cast(bf16x8, uh);
    f.l = __builtin_bit_cast(bf16x8, ul);
    return f;
}

static __device__ inline bf16x8 pack_bf8(float4 x0, float4 x1) {
    float v[8] = {x0.x, x0.y, x0.z, x0.w, x1.x, x1.y, x1.z, x1.w};
    ushort8 u;
#pragma unroll
    for (int j = 0; j < 8; ++j) u[j] = f2bf(v[j]);
    return __builtin_bit_cast(bf16x8, u);
}

static __device__ inline bf16x8 load_bf8(const float* __restrict__ p) {
    float4 x0 = *reinterpret_cast<const float4*>(p);
    float4 x1 = *reinterpret_cast<const float4*>(p + 4);
    return pack_bf8(x0, x1);
}

static __device__ inline bf16x8 load_bf8_strided(const float* __restrict__ p, int stride) {
    ushort8 u;
#pragma unroll
    for (int j = 0; j < 8; ++j) u[j] = f2bf(p[(size_t)j * stride]);
    return __builtin_bit_cast(bf16x8, u);
}

#define MFMA(a, b, c) __builtin_amdgcn_mfma_f32_16x16x32_bf16((a), (b), (c), 0, 0, 0)

// async global -> LDS, 16B per lane; lds dest is wave-uniform base + lane*16
#define GLLD(g, s)                                                              \
    __builtin_amdgcn_global_load_lds(                                           \
        (const __attribute__((address_space(1))) void*)(g),                     \
        (__attribute__((address_space(3))) void*)(s), 16, 0, 0)

// stage a 64x64 fp32 tile (rows at src0 + row*DH) into buf[b]; WAVE-PRIVATE:
// wave w stages rows [w*16, w*16+16) and later reads only those rows.
// source pre-swizzled (chunk ^= row&7) so linear LDS + swizzled reads match.
#define STAGE64(src0, b)                                                        \
    do {                                                                        \
        _Pragma("unroll")                                                       \
        for (int j_ = 0; j_ < 4; ++j_) {                                        \
            const int idx_ = w * 256 + j_ * 64 + l;                             \
            const int row_ = idx_ >> 4;                                         \
            const int g_ = (idx_ & 15) ^ (row_ & 7);                            \
            GLLD((src0) + (size_t)row_ * DH + g_ * 4,                           \
                 &buf[b][w * 256 + j_ * 64]);                                   \
        }                                                                       \
    } while (0)

// ---------------- K1: content scores Q@K^T * scale -> P (zeros above diag).
// Block = (q-tile 64, bh). One barrier per tile; stage(t+1) issued after it.
__global__ __launch_bounds__(256, 4) void k_scores(const float* __restrict__ qp,
                                                   const float* __restrict__ kp,
                                                   float* __restrict__ P) {
    __shared__ float4 buf[2][1024];
    const int x = blockIdx.x;
    const int qt = (x & 1) ? (x >> 1) : (15 - (x >> 1));  // alternate big/small
    const int bh = blockIdx.y;
    const int tid = threadIdx.x;
    const int w = tid >> 6, l = tid & 63;
    const int lm = l & 15, lg = l >> 4;
    const int q0 = qt * 64;

    Frag2 qh0[4], qh1[4];  // pre-scaled by SCALE
#pragma unroll
    for (int nt = 0; nt < 4; ++nt) {
        const float* qrow = qp + ((size_t)bh * SQ + q0 + nt * 16 + lm) * DH + lg * 8;
        qh0[nt] = load_split(qrow, SCALE);
        qh1[nt] = load_split(qrow + 32, SCALE);
    }
    const float* kb = kp + (size_t)bh * SK * DH;
    const int nt_ = qt + 1;

    STAGE64(kb, 0);
#pragma unroll 1
    for (int t = 0; t < nt_; ++t) {
        __syncthreads();  // drains stage(t)
        if (t + 1 < nt_) STAGE64(kb + (size_t)(t + 1) * 64 * DH, (t + 1) & 1);
        const float4* L = buf[t & 1];
        const int R = w * 16 + lm;
        const int sw = R & 7;
        float4 f0 = L[R * 16 + ((2 * lg) ^ sw)];
        float4 f1 = L[R * 16 + ((2 * lg + 1) ^ sw)];
        float4 f2 = L[R * 16 + ((8 + 2 * lg) ^ sw)];
        float4 f3 = L[R * 16 + ((9 + 2 * lg) ^ sw)];
        bf16x8 alo = pack_bf8(f0, f1);
        bf16x8 ahi = pack_bf8(f2, f3);
        const int kq = t * 64 + w * 16 + lg * 4;
        const bool diag = (t == qt);
#pragma unroll
        for (int nt = 0; nt < 4; ++nt) {
            f32x4 acc = {0.f, 0.f, 0.f, 0.f};
            acc = MFMA(alo, qh0[nt].h, acc);
            acc = MFMA(alo, qh0[nt].l, acc);
            acc = MFMA(ahi, qh1[nt].h, acc);
            acc = MFMA(ahi, qh1[nt].l, acc);
            const int qe = q0 + nt * 16 + lm;
            float ov[4];
#pragma unroll
            for (int r = 0; r < 4; ++r)
                ov[r] = (!diag || (kq + r <= qe)) ? acc[r] : 0.f;
            float4 o;
            o.x = ov[0]; o.y = ov[1]; o.z = ov[2]; o.w = ov[3];
            *reinterpret_cast<float4*>(&P[((size_t)bh * SQ + qe) * SK + kq]) = o;
        }
    }
    // zero-fill tiles fully above the diagonal
    const float4 z = {0.f, 0.f, 0.f, 0.f};
#pragma unroll 1
    for (int t = nt_; t < 16; ++t) {
        const int kq = t * 64 + w * 16 + lg * 4;
#pragma unroll
        for (int nt = 0; nt < 4; ++nt) {
            const int qe = q0 + nt * 16 + lm;
            *reinterpret_cast<float4*>(&P[((size_t)bh * SQ + qe) * SK + kq]) = z;
        }
    }
}

// ---------------- K2: fused rel+exp+normalize+P@bigr_v. Block per q (balanced).
__global__ __launch_bounds__(256, 4) void k_rel_pr(const float* __restrict__ query,
                                                   const float* __restrict__ bigr_k,
                                                   const float* __restrict__ bigr_v,
                                                   float* __restrict__ P,
                                                   float* __restrict__ out) {
    __shared__ float4 buf[2][1024];  // pass1 tiles; pass2: reused as vt[2][64][36]
    __shared__ float red[4][64];
    __shared__ float rsum[64];
    // balanced remap: per-CU stripes sum to 2046 regardless of CU index
    int q;
    {
        const int bid = blockIdx.x, c = bid & 255;
        switch (bid >> 8) {
            case 0:  q = 1023 - c; break;
            case 1:  q = c;        break;
            case 2:  q = 767 - c;  break;
            default: q = 256 + c;  break;
        }
    }
    const int KE = q + 1;
    const int nt_ = (KE + 63) >> 6;
    const int tid = threadIdx.x;
    const int w = tid >> 6, l = tid & 63;
    const int lm = l & 15, lg = l >> 4;

    // ---- pass 1: e = exp(content + rel), row sums ----
    Frag2 qh0[4], qh1[4];  // pre-scaled
    float* prow[4];
#pragma unroll
    for (int nt = 0; nt < 4; ++nt) {
        const int bh = nt * 16 + lm;
        const float* qrow = query + ((size_t)bh * SQ + q) * DH + lg * 8;
        qh0[nt] = load_split(qrow, SCALE);
        qh1[nt] = load_split(qrow + 32, SCALE);
        prow[nt] = P + ((size_t)bh * SQ + q) * SK;
    }
    const float* bk = bigr_k + (size_t)q * SK * DH;
    float lsum[4] = {0.f, 0.f, 0.f, 0.f};

    STAGE64(bk, 0);
    float4 pcA[4], pcB[4];
    {
        const int kq0 = w * 16 + lg * 4;
#pragma unroll
        for (int nt = 0; nt < 4; ++nt)
            pcA[nt] = *reinterpret_cast<const float4*>(prow[nt] + kq0);
    }
#pragma unroll 1
    for (int t = 0; t < nt_; ++t) {
        __syncthreads();  // drains stage(t) + pc(t); stage(t+1) issued below
        if (t + 1 < nt_) {
            STAGE64(bk + (size_t)(t + 1) * 64 * DH, (t + 1) & 1);
            const int kqn = (t + 1) * 64 + w * 16 + lg * 4;
#pragma unroll
            for (int nt = 0; nt < 4; ++nt)
                pcB[nt] = *reinterpret_cast<const float4*>(prow[nt] + kqn);
        }
        const float4* L = buf[t & 1];
        const int R = w * 16 + lm;
        const int sw = R & 7;
        float4 f0 = L[R * 16 + ((2 * lg) ^ sw)];
        float4 f1 = L[R * 16 + ((2 * lg + 1) ^ sw)];
        float4 f2 = L[R * 16 + ((8 + 2 * lg) ^ sw)];
        float4 f3 = L[R * 16 + ((9 + 2 * lg) ^ sw)];
        bf16x8 alo = pack_bf8(f0, f1);
        bf16x8 ahi = pack_bf8(f2, f3);
        const int kq = t * 64 + w * 16 + lg * 4;
#pragma unroll
        for (int nt = 0; nt < 4; ++nt) {
            f32x4 acc = {0.f, 0.f, 0.f, 0.f};
            acc = MFMA(alo, qh0[nt].h, acc);
            acc = MFMA(alo, qh0[nt].l, acc);
            acc = MFMA(ahi, qh1[nt].h, acc);
            acc = MFMA(ahi, qh1[nt].l, acc);
            const float4 c = pcA[nt];
            float cv[4] = {c.x, c.y, c.z, c.w};
            float ov[4];
#pragma unroll
            for (int r = 0; r < 4; ++r) {
                float e = (kq + r < KE) ? __expf(cv[r] + acc[r]) : 0.f;
                ov[r] = e;
                lsum[nt] += e;
            }
            float4 o;
            o.x = ov[0]; o.y = ov[1]; o.z = ov[2]; o.w = ov[3];
            *reinterpret_cast<float4*>(prow[nt] + kq) = o;
        }
        if (t + 1 < nt_) {
#pragma unroll
            for (int nt = 0; nt < 4; ++nt) pcA[nt] = pcB[nt];
        }
    }

    // ---- row-sum reduce -> recip in LDS ----
#pragma unroll
    for (int nt = 0; nt < 4; ++nt) {
        float v = lsum[nt];
        v += __shfl_xor(v, 16);
        v += __shfl_xor(v, 32);
        if (l < 16) red[w][nt * 16 + l] = v;
    }
    __syncthreads();
    if (tid < 64)
        rsum[tid] = 1.0f / (red[0][tid] + red[1][tid] + red[2][tid] + red[3][tid]);
    __syncthreads();  // rsum visible; pass1 buf reads complete before vt reuse

    // ---- pass 2: normalize P in place + out = Pn @ bigr_v[q]; dbuf vt ----
    float* vtf = reinterpret_cast<float*>(&buf[0][0]);  // [2][64][36] floats
    const int bh0 = w * 16;
    const int skk = tid & 31, sdd = (tid >> 5) * 8;
    const float* bv = bigr_v + (size_t)q * SK * DH;
    float* arow0 = P + ((size_t)(bh0 + lm) * SQ + q) * SK + lg * 8;
    const float nrm = rsum[bh0 + lm];
    const int nsteps = (KE + 31) >> 5;
    f32x4 acc[4] = {{0.f,0.f,0.f,0.f},{0.f,0.f,0.f,0.f},{0.f,0.f,0.f,0.f},{0.f,0.f,0.f,0.f}};

    float4 va, vb;
    {
        const float* src = bv + (size_t)skk * DH + sdd;
        va = *reinterpret_cast<const float4*>(src);
        vb = *reinterpret_cast<const float4*>(src + 4);
    }
#pragma unroll 1
    for (int s = 0; s < nsteps; ++s) {
        float* V = vtf + (s & 1) * 2304;  // 64*36
        V[(sdd + 0) * 36 + skk] = va.x; V[(sdd + 1) * 36 + skk] = va.y;
        V[(sdd + 2) * 36 + skk] = va.z; V[(sdd + 3) * 36 + skk] = va.w;
        V[(sdd + 4) * 36 + skk] = vb.x; V[(sdd + 5) * 36 + skk] = vb.y;
        V[(sdd + 6) * 36 + skk] = vb.z; V[(sdd + 7) * 36 + skk] = vb.w;
        if (s + 1 < nsteps) {  // issue next chunk early (consumed next iter)
            const float* src = bv + (size_t)((s + 1) * 32 + skk) * DH + sdd;
            va = *reinterpret_cast<const float4*>(src);
            vb = *reinterpret_cast<const float4*>(src + 4);
        }
        __syncthreads();  // vt[s&1] written by all waves
        const int k0 = s * 32;
        float* arow = arow0 + k0;
        float4 x0 = *reinterpret_cast<const float4*>(arow);
        float4 x1 = *reinterpret_cast<const float4*>(arow + 4);
        float4 y0 = {x0.x * nrm, x0.y * nrm, x0.z * nrm, x0.w * nrm};
        float4 y1 = {x1.x * nrm, x1.y * nrm, x1.z * nrm, x1.w * nrm};
        *reinterpret_cast<float4*>(arow) = y0;       // final normalized p_attn
        *reinterpret_cast<float4*>(arow + 4) = y1;
        bf16x8 a = pack_bf8(y0, y1);
#pragma unroll
        for (int nt = 0; nt < 4; ++nt) {
            const float* bp = V + (nt * 16 + lm) * 36 + lg * 8;
            float4 u0 = *reinterpret_cast<const float4*>(bp);
            float4 u1 = *reinterpret_cast<const float4*>(bp + 4);
            acc[nt] = MFMA(a, pack_bf8(u0, u1), acc[nt]);
        }
    }
#pragma unroll
    for (int nt = 0; nt < 4; ++nt)
#pragma unroll
        for (int r = 0; r < 4; ++r)
            out[((size_t)(bh0 + lg * 4 + r) * SQ + q) * DH + nt * 16 + lm] = acc[nt][r];
}

// ---------------- K3: out += Pn @ V (per bh, q-tiles of 64)
__global__ __launch_bounds__(256) void k_pv(const float* __restrict__ P,
                                            const float* __restrict__ V,
                                            float* __restrict__ out) {
    const int x = blockIdx.x;
    const int qt = (x & 1) ? (x >> 1) : (15 - (x >> 1));  // alternate big/small
    const int bh = blockIdx.y;
    const int tid = threadIdx.x;
    const int w = tid >> 6, l = tid & 63;
    const int lm = l & 15, lg = l >> 4;
    const int q0 = qt * 64 + w * 16;

    f32x4 acc[4] = {{0.f,0.f,0.f,0.f},{0.f,0.f,0.f,0.f},{0.f,0.f,0.f,0.f},{0.f,0.f,0.f,0.f}};
    const int kend = q0 + 16;
    for (int k0 = 0; k0 < kend; k0 += 32) {
        const float* arow = P + ((size_t)bh * SQ + q0 + lm) * SK + k0 + lg * 8;
        bf16x8 a = load_bf8(arow);
#pragma unroll
        for (int nt = 0; nt < 4; ++nt) {
            const float* bcol = V + ((size_t)bh * SK + k0 + lg * 8) * DH + nt * 16 + lm;
            bf16x8 b = load_bf8_strided(bcol, DH);
            acc[nt] = MFMA(a, b, acc[nt]);
        }
    }
#pragma unroll
    for (int nt = 0; nt < 4; ++nt)
#pragma unroll
        for (int r = 0; r < 4; ++r)
            out[((size_t)bh * SQ + q0 + lg * 4 + r) * DH + nt * 16 + lm] += acc[nt][r];
}

extern "C" void kernel_launch(void* const* d_in, const int* in_sizes, int n_in,
                              void* d_out, int out_size, void* d_ws, size_t ws_size,
                              hipStream_t stream) {
    const float* query  = (const float*)d_in[0];
    const float* key    = (const float*)d_in[1];
    const float* value  = (const float*)d_in[2];
    const float* bigr_k = (const float*)d_in[3];
    const float* bigr_v = (const float*)d_in[4];
    float* out = (float*)d_out;                       // BH*SQ*DH
    float* P   = out + (size_t)BH * SQ * DH;          // BH*SQ*SK

    k_scores<<<dim3(16, BH), 256, 0, stream>>>(query, key, P);
    k_rel_pr<<<dim3(SQ), 256, 0, stream>>>(query, bigr_k, bigr_v, P, out);
    k_pv<<<dim3(16, BH), 256, 0, stream>>>(P, value, out);
}